// Round 12
// baseline (1117.179 us; speedup 1.0000x reference)
//
#include <hip/hip_runtime.h>

#define NN 50000
#define NE 800000
#define HD 128
#define TPB 4   // edge tiles (of 64) per block

typedef short short8 __attribute__((ext_vector_type(8)));
typedef float floatx4 __attribute__((ext_vector_type(4)));

static __device__ __forceinline__ unsigned short f2bf(float f) {
    unsigned int u = __float_as_uint(f);
    unsigned int lsb = (u >> 16) & 1u;
    u += 0x7fffu + lsb;
    return (unsigned short)(u >> 16);
}

// HW packed f32->bf16 (RNE), 2 elems/instr; lo=src0, hi=src1.
static __device__ __forceinline__ short8 pack2(float4 a, float4 b) {
    union { unsigned int u[4]; short8 s; } r;
    asm("v_cvt_pk_bf16_f32 %0, %1, %2" : "=v"(r.u[0]) : "v"(a.x), "v"(a.y));
    asm("v_cvt_pk_bf16_f32 %0, %1, %2" : "=v"(r.u[1]) : "v"(a.z), "v"(a.w));
    asm("v_cvt_pk_bf16_f32 %0, %1, %2" : "=v"(r.u[2]) : "v"(b.x), "v"(b.y));
    asm("v_cvt_pk_bf16_f32 %0, %1, %2" : "=v"(r.u[3]) : "v"(b.z), "v"(b.w));
    return r.s;
}

static __device__ __forceinline__ floatx4 mfma16x16x32(short8 a, short8 b, floatx4 c) {
    asm("v_mfma_f32_16x16x32_bf16 %0, %1, %2, %0" : "+v"(c) : "v"(a), "v"(b));
    return c;
}

// Hazard guards: inline-asm MFMA is invisible to LLVM's GCNHazardRecognizer.
// Register-cap ledger (msg_kernel): attr 4 -> no scratch (r8/r11, WRITE=31MB).
// attr 6/8 force sub-natural allocations + scratch (r9/r10). Keep attr=4.
#define NOPGUARD_INIT8(A) asm volatile("s_nop 3" \
  : "+v"(A[0]),"+v"(A[1]),"+v"(A[2]),"+v"(A[3]),"+v"(A[4]),"+v"(A[5]),"+v"(A[6]),"+v"(A[7]))
#define NOPGUARD8(A) asm volatile("s_nop 7\ns_nop 7" \
  : "+v"(A[0]),"+v"(A[1]),"+v"(A[2]),"+v"(A[3]),"+v"(A[4]),"+v"(A[5]),"+v"(A[6]),"+v"(A[7]))

// ---------------- weight packing (unchanged) ----------------
__global__ void pack_weights(const float* __restrict__ mW1, const float* __restrict__ mW2,
                             const float* __restrict__ uW1, const float* __restrict__ uW2,
                             unsigned short* __restrict__ W1p, unsigned short* __restrict__ W2p,
                             unsigned short* __restrict__ U1p, unsigned short* __restrict__ U2p) {
    int t = blockIdx.x * 256 + threadIdx.x;
    const float* src; unsigned short* dst; int kmax; int i;
    if (t < 40960)        { src = mW1; dst = W1p; kmax = 291; i = t; }
    else if (t < 57344)   { src = mW2; dst = W2p; kmax = 128; i = t - 40960; }
    else if (t < 90112)   { src = uW1; dst = U1p; kmax = 256; i = t - 57344; }
    else if (t < 106496)  { src = uW2; dst = U2p; kmax = 128; i = t - 90112; }
    else return;
    int j = i & 7;
    int lane = (i >> 3) & 63;
    int n = (i >> 9) & 7;
    int kk = i >> 12;
    int k = kk * 32 + ((lane >> 4) << 3) + j;
    int c = n * 16 + (lane & 15);
    float v = (k < kmax) ? src[k * 128 + c] : 0.0f;
    dst[i] = f2bf(v);
}

// ---------------- fp32 -> bf16 cast (x at rest) ----------------
__global__ void cast_kernel(const float* __restrict__ in, unsigned short* __restrict__ out,
                            int n8) {
    int t = blockIdx.x * 256 + threadIdx.x;
    if (t < n8) {
        float4 a = *reinterpret_cast<const float4*>(in + (size_t)t * 8);
        float4 b = *reinterpret_cast<const float4*>(in + (size_t)t * 8 + 4);
        *reinterpret_cast<short8*>(out + (size_t)t * 8) = pack2(a, b);
    }
}

// ---------------- CSR build: hist -> scan -> scatter ----------------
__global__ void hist_kernel(const int* __restrict__ ei, int* __restrict__ counts) {
    int e = blockIdx.x * 256 + threadIdx.x;
    if (e < NE) atomicAdd(&counts[ei[NE + e]], 1);
}

__global__ __launch_bounds__(1024)
void scan1_kernel(const int* __restrict__ counts, int* __restrict__ partial,
                  int* __restrict__ bsum) {
    __shared__ int wsum[16];
    int tid = threadIdx.x;
    int gid = blockIdx.x * 1024 + tid;
    int lane = tid & 63, w = tid >> 6;
    int v = (gid < NN) ? counts[gid] : 0;
    int s = v;
    #pragma unroll
    for (int o = 1; o < 64; o <<= 1) { int t = __shfl_up(s, o); if (lane >= o) s += t; }
    if (lane == 63) wsum[w] = s;
    __syncthreads();
    if (w == 0 && lane < 16) {
        int t = wsum[lane];
        #pragma unroll
        for (int o = 1; o < 16; o <<= 1) { int u = __shfl_up(t, o); if (lane >= o) t += u; }
        wsum[lane] = t;
    }
    __syncthreads();
    int base = (w > 0) ? wsum[w - 1] : 0;
    if (gid < NN) partial[gid] = base + s - v;
    if (tid == 1023) bsum[blockIdx.x] = base + s;
}

__global__ void scan2_kernel(int* __restrict__ bsum, int n) {
    int lane = threadIdx.x;
    int v = (lane < n) ? bsum[lane] : 0;
    int s = v;
    #pragma unroll
    for (int o = 1; o < 64; o <<= 1) { int t = __shfl_up(s, o); if (lane >= o) s += t; }
    if (lane < n) bsum[lane] = s - v;
}

// Writes packed (src | dst<<16), precomputed bf16 rel_coords, AND the bf16
// edge_attr row -- all at the dst-sorted position.
__global__ void scatter_kernel(const int* __restrict__ ei, const int* __restrict__ partial,
                               const int* __restrict__ bsum, int* __restrict__ cursor,
                               const float* __restrict__ cd, const float* __restrict__ ea,
                               unsigned int* __restrict__ epack,
                               uint2* __restrict__ relb,
                               unsigned short* __restrict__ eab) {
    int e = blockIdx.x * 256 + threadIdx.x;
    if (e < NE) {
        int d = ei[NE + e];
        int s = ei[e];
        int pos = partial[d] + bsum[d >> 10] + atomicAdd(&cursor[d], 1);
        epack[pos] = (unsigned int)s | ((unsigned int)d << 16);
        float r0 = cd[d * 3 + 0] - cd[s * 3 + 0];
        float r1 = cd[d * 3 + 1] - cd[s * 3 + 1];
        float r2 = cd[d * 3 + 2] - cd[s * 3 + 2];
        uint2 rr;
        asm("v_cvt_pk_bf16_f32 %0, %1, %2" : "=v"(rr.x) : "v"(r0), "v"(r1));
        asm("v_cvt_pk_bf16_f32 %0, %1, %2" : "=v"(rr.y) : "v"(r2), "v"(0.0f));
        relb[pos] = rr;
        const float* eap = ea + (size_t)e * 32;
        unsigned short* eo = eab + (size_t)pos * 32;
        #pragma unroll
        for (int q = 0; q < 4; ++q) {
            float4 a = *reinterpret_cast<const float4*>(eap + q * 8);
            float4 b = *reinterpret_cast<const float4*>(eap + q * 8 + 4);
            *reinterpret_cast<short8*>(eo + q * 8) = pack2(a, b);
        }
    }
}

// ---------------- message MLP: T=4 software-pipelined tiles per block ----------------
// 256 dst-sorted edges per block (4 tiles of 64), 4 waves. Tile t+1's gathers
// are issued right after tile t's layer-1 consumes the current fragments, so
// HBM/L2 gather latency hides under tile t's epilogue (LDS+MFMA+atomics).
__global__ __launch_bounds__(256, 4)
void msg_kernel(const unsigned short* __restrict__ xb, const unsigned short* __restrict__ eab,
                const unsigned int* __restrict__ epack, const uint2* __restrict__ relb,
                const unsigned short* __restrict__ W1p, const float* __restrict__ mb1,
                const unsigned short* __restrict__ W2p, const float* __restrict__ mb2,
                float* __restrict__ aggr) {
    __shared__ unsigned short sH[64 * 136];   // hidden tile, then bf16 out tile
    __shared__ int sDst[TPB][64];
    __shared__ unsigned int headm[TPB][2];

    const int tid = threadIdx.x;
    const int lane = tid & 63;
    const int wid = tid >> 6;
    const int g = lane >> 4;
    const int lr = lane & 15;
    const int arow = wid * 16 + lr;
    const int base = blockIdx.x * (TPB * 64);

    // Prologue: all tile headers, then tile-0 gathers.
    unsigned int pk[TPB];
    #pragma unroll
    for (int t = 0; t < TPB; ++t) pk[t] = epack[base + t * 64 + arow];

    short8 px[8];   // x_src / x_dst fragments (current tile in flight)
    short8 pe;      // edge_attr fragment
    uint2  pr;      // rel bf16x4

#define PF_TILE(tt) do {                                                        \
        unsigned int p_ = pk[tt];                                               \
        int src_ = (int)(p_ & 0xFFFFu);                                         \
        int dst_ = (int)(p_ >> 16);                                             \
        if (g == 0) sDst[tt][arow] = dst_;                                      \
        const unsigned short* xs_ = xb + (size_t)src_ * 128 + g * 8;            \
        const unsigned short* xd_ = xb + (size_t)dst_ * 128 + g * 8;            \
        _Pragma("unroll")                                                       \
        for (int kk_ = 0; kk_ < 4; ++kk_) {                                     \
            px[kk_]     = *reinterpret_cast<const short8*>(xs_ + kk_ * 32);     \
            px[4 + kk_] = *reinterpret_cast<const short8*>(xd_ + kk_ * 32);     \
        }                                                                       \
        pe = *reinterpret_cast<const short8*>(eab + (size_t)(base + (tt) * 64 + arow) * 32 + g * 8); \
        pr = relb[base + (tt) * 64 + arow];                                     \
    } while (0)

    PF_TILE(0);
    __syncthreads();   // sDst[0] visible to wave 0 for headm

    #pragma unroll
    for (int t = 0; t < TPB; ++t) {
        // rel fragment for this tile (k 288..295; g==0 lanes carry rel).
        union { unsigned int u[4]; short8 s; } a9;
        a9.u[0] = (g == 0) ? pr.x : 0u;
        a9.u[1] = (g == 0) ? pr.y : 0u;
        a9.u[2] = 0u; a9.u[3] = 0u;
        const short8 af9 = a9.s;
        const short8 af8 = pe;

        // Layer 1: (64x320) @ (320x128)
        floatx4 acc[8];
        #pragma unroll
        for (int n = 0; n < 8; ++n)
            #pragma unroll
            for (int r = 0; r < 4; ++r) acc[n][r] = 0.0f;
        NOPGUARD_INIT8(acc);

        #pragma unroll
        for (int kk = 0; kk < 8; ++kk) {
            const short8* wb = reinterpret_cast<const short8*>(W1p) + (kk * 8) * 64 + lane;
            #pragma unroll
            for (int n = 0; n < 8; ++n)
                acc[n] = mfma16x16x32(px[kk], wb[n * 64], acc[n]);
        }
        {
            const short8* wb8 = reinterpret_cast<const short8*>(W1p) + (8 * 8) * 64 + lane;
            const short8* wb9 = reinterpret_cast<const short8*>(W1p) + (9 * 8) * 64 + lane;
            #pragma unroll
            for (int n = 0; n < 8; ++n)
                acc[n] = mfma16x16x32(af8, wb8[n * 64], acc[n]);
            #pragma unroll
            for (int n = 0; n < 8; ++n)
                acc[n] = mfma16x16x32(af9, wb9[n * 64], acc[n]);
        }
        NOPGUARD8(acc);

        // Issue next tile's gathers now: latency hides under this epilogue.
        if (t < TPB - 1) PF_TILE(t + 1);

        // Segment-head bitmask for this tile (wave 0).
        if (tid < 64) {
            bool head = (tid == 0) || (sDst[t][tid] != sDst[t][tid - 1]);
            unsigned long long m = __ballot(head);
            if (tid == 0) { headm[t][0] = (unsigned int)m; headm[t][1] = (unsigned int)(m >> 32); }
        }

        // bias + ReLU -> sH (bf16)
        #pragma unroll
        for (int n = 0; n < 8; ++n) {
            float bias = mb1[n * 16 + lr];
            #pragma unroll
            for (int r = 0; r < 4; ++r) {
                int row = wid * 16 + g * 4 + r;
                sH[row * 136 + n * 16 + lr] = f2bf(fmaxf(acc[n][r] + bias, 0.0f));
            }
        }
        __syncthreads();

        // Pull layer-2 A fragments, then the buffer is reused for the out tile.
        short8 a2[4];
        #pragma unroll
        for (int kk = 0; kk < 4; ++kk)
            a2[kk] = *reinterpret_cast<const short8*>(&sH[arow * 136 + kk * 32 + g * 8]);
        __syncthreads();

        // Layer 2: (64x128) @ (128x128)
        floatx4 acc2[8];
        #pragma unroll
        for (int n = 0; n < 8; ++n)
            #pragma unroll
            for (int r = 0; r < 4; ++r) acc2[n][r] = 0.0f;
        NOPGUARD_INIT8(acc2);

        #pragma unroll
        for (int kk = 0; kk < 4; ++kk) {
            const short8* wb = reinterpret_cast<const short8*>(W2p) + (kk * 8) * 64 + lane;
            #pragma unroll
            for (int n = 0; n < 8; ++n)
                acc2[n] = mfma16x16x32(a2[kk], wb[n * 64], acc2[n]);
        }
        NOPGUARD8(acc2);

        // bias -> bf16 LDS out tile
        #pragma unroll
        for (int n = 0; n < 8; ++n) {
            float bias = mb2[n * 16 + lr];
            #pragma unroll
            for (int r = 0; r < 4; ++r) {
                int row = wid * 16 + g * 4 + r;
                sH[row * 136 + n * 16 + lr] = f2bf(acc2[n][r] + bias);
            }
        }
        __syncthreads();

        // Bitmask segmented reduction: one atomic row per distinct dst.
        {
            const unsigned long long hm =
                ((unsigned long long)headm[t][1] << 32) | (unsigned long long)headm[t][0];
            const int col = tid & 127;
            const int half = tid >> 7;
            unsigned long long m = hm;
            int sidx = 0;
            while (m) {
                int start = __ffsll((long long)m) - 1;
                unsigned long long m2 = m & (m - 1);
                int end = m2 ? (__ffsll((long long)m2) - 1) : 64;
                if ((sidx & 1) == half) {
                    float sum = 0.0f;
                    for (int r = start; r < end; ++r) {
                        unsigned int uu = sH[r * 136 + col];
                        sum += __uint_as_float(uu << 16);
                    }
                    atomicAdd(&aggr[sDst[t][start] * 128 + col], sum);
                }
                m = m2; ++sidx;
            }
        }
        __syncthreads();   // protect sH before next tile's bias/ReLU writes
    }
#undef PF_TILE
}

// ---------------- node update MLP + residual + LayerNorm (unchanged) ----------------
__global__ __launch_bounds__(256, 4)
void node_kernel(const unsigned short* __restrict__ xb, const float* __restrict__ x,
                 const float* __restrict__ aggr,
                 const unsigned short* __restrict__ U1p, const float* __restrict__ ub1,
                 const unsigned short* __restrict__ U2p, const float* __restrict__ ub2,
                 const float* __restrict__ gamma, const float* __restrict__ beta,
                 float* __restrict__ out) {
    __shared__ unsigned short sH[64 * 136];

    const int tid = threadIdx.x;
    const int lane = tid & 63;
    const int wid = tid >> 6;
    const int g = lane >> 4;
    const int lr = lane & 15;
    const int arow = wid * 16 + lr;
    const int n0 = blockIdx.x * 64;

    int nd0 = n0 + arow;
    int ndc0 = (nd0 < NN) ? nd0 : (NN - 1);

    const unsigned short* xp = xb + (size_t)ndc0 * 128 + g * 8;
    const float* ap = aggr + (size_t)ndc0 * 128 + g * 8;

    short8 af[8];
    float4 ta[8];
    #pragma unroll
    for (int kk = 0; kk < 4; ++kk) {
        af[kk] = *reinterpret_cast<const short8*>(xp + kk * 32);
        ta[2 * kk]     = *reinterpret_cast<const float4*>(ap + kk * 32);
        ta[2 * kk + 1] = *reinterpret_cast<const float4*>(ap + kk * 32 + 4);
    }
    #pragma unroll
    for (int kk = 0; kk < 4; ++kk)
        af[4 + kk] = pack2(ta[2 * kk], ta[2 * kk + 1]);

    // Layer 1: (64x256) @ (256x128)
    floatx4 acc[8];
    #pragma unroll
    for (int n = 0; n < 8; ++n)
        #pragma unroll
        for (int r = 0; r < 4; ++r) acc[n][r] = 0.0f;
    NOPGUARD_INIT8(acc);

    #pragma unroll
    for (int kk = 0; kk < 8; ++kk) {
        const short8* wb = reinterpret_cast<const short8*>(U1p) + (kk * 8) * 64 + lane;
        #pragma unroll
        for (int n = 0; n < 8; ++n)
            acc[n] = mfma16x16x32(af[kk], wb[n * 64], acc[n]);
    }
    NOPGUARD8(acc);

    #pragma unroll
    for (int n = 0; n < 8; ++n) {
        float bias = ub1[n * 16 + lr];
        #pragma unroll
        for (int r = 0; r < 4; ++r) {
            int row = wid * 16 + g * 4 + r;
            sH[row * 136 + n * 16 + lr] = f2bf(fmaxf(acc[n][r] + bias, 0.0f));
        }
    }
    __syncthreads();

    short8 a2[4];
    #pragma unroll
    for (int kk = 0; kk < 4; ++kk)
        a2[kk] = *reinterpret_cast<const short8*>(&sH[arow * 136 + kk * 32 + g * 8]);

    // Layer 2: (64x128) @ (128x128)
    floatx4 acc2[8];
    #pragma unroll
    for (int n = 0; n < 8; ++n)
        #pragma unroll
        for (int r = 0; r < 4; ++r) acc2[n][r] = 0.0f;
    NOPGUARD_INIT8(acc2);

    #pragma unroll
    for (int kk = 0; kk < 4; ++kk) {
        const short8* wb = reinterpret_cast<const short8*>(U2p) + (kk * 8) * 64 + lane;
        #pragma unroll
        for (int n = 0; n < 8; ++n)
            acc2[n] = mfma16x16x32(a2[kk], wb[n * 64], acc2[n]);
    }
    NOPGUARD8(acc2);

    // Epilogue: residual + LayerNorm in registers (16-lane shfl_xor row-reduce).
    #pragma unroll
    for (int r = 0; r < 4; ++r) {
        int row = wid * 16 + g * 4 + r;
        int nd = n0 + row;
        int ndc = (nd < NN) ? nd : (NN - 1);
        float vals[8];
        float s1 = 0.0f, s2 = 0.0f;
        #pragma unroll
        for (int n = 0; n < 8; ++n) {
            int col = n * 16 + lr;
            float v = acc2[n][r] + ub2[col] + x[ndc * 128 + col];
            vals[n] = v;
            s1 += v;
            s2 += v * v;
        }
        #pragma unroll
        for (int m = 1; m < 16; m <<= 1) {
            s1 += __shfl_xor(s1, m);
            s2 += __shfl_xor(s2, m);
        }
        float mean = s1 * (1.0f / 128.0f);
        float var = s2 * (1.0f / 128.0f) - mean * mean;
        float inv = rsqrtf(var + 1e-5f);
        if (nd < NN) {
            #pragma unroll
            for (int n = 0; n < 8; ++n) {
                int col = n * 16 + lr;
                out[nd * 128 + col] = (vals[n] - mean) * inv * gamma[col] + beta[col];
            }
        }
    }
}

extern "C" void kernel_launch(void* const* d_in, const int* in_sizes, int n_in,
                              void* d_out, int out_size, void* d_ws, size_t ws_size,
                              hipStream_t stream) {
    const float* x     = (const float*)d_in[0];
    const int*   ei    = (const int*)d_in[1];
    const float* ea    = (const float*)d_in[2];
    const float* cd    = (const float*)d_in[3];
    const float* mW1   = (const float*)d_in[4];
    const float* mb1   = (const float*)d_in[5];
    const float* mW2   = (const float*)d_in[6];
    const float* mb2   = (const float*)d_in[7];
    const float* uW1   = (const float*)d_in[8];
    const float* ub1   = (const float*)d_in[9];
    const float* uW2   = (const float*)d_in[10];
    const float* ub2   = (const float*)d_in[11];
    const float* gamma = (const float*)d_in[12];
    const float* beta  = (const float*)d_in[13];
    float* out = (float*)d_out;

    char* ws = (char*)d_ws;
    unsigned short* W1p = (unsigned short*)(ws);                     // 81,920 B
    unsigned short* W2p = (unsigned short*)(ws + 81920);             // 32,768 B
    unsigned short* U1p = (unsigned short*)(ws + 114688);            // 65,536 B
    unsigned short* U2p = (unsigned short*)(ws + 180224);            // 32,768 B
    int* counts  = (int*)(ws + 212992);                              // 200,704 B
    int* cursor  = (int*)(ws + 413696);                              // 200,704 B (adjacent: one memset)
    int* partial = (int*)(ws + 614400);                              // 200,704 B
    int* bsum    = (int*)(ws + 815104);                              // 256 B
    unsigned int* epack = (unsigned int*)(ws + 815360);              // 3,200,000 B
    uint2* relb  = (uint2*)(ws + 4015360);                           // 6,400,000 B
    unsigned short* xbuf = (unsigned short*)(ws + 10415360);         // 12,800,000 B
    unsigned short* eabuf = (unsigned short*)(ws + 23215360);        // 51,200,000 B
    // total ws use: 74,415,360 B

    float* aggr = out;   // aggr lives in d_out (exactly NN*HD floats)

    hipMemsetAsync(counts, 0, (size_t)(614400 - 212992), stream);
    hipMemsetAsync(aggr, 0, (size_t)NN * HD * sizeof(float), stream);

    pack_weights<<<416, 256, 0, stream>>>(mW1, mW2, uW1, uW2, W1p, W2p, U1p, U2p);
    cast_kernel<<<(NN * HD / 8 + 255) / 256, 256, 0, stream>>>(x, xbuf, NN * HD / 8);
    hist_kernel<<<(NE + 255) / 256, 256, 0, stream>>>(ei, counts);
    scan1_kernel<<<(NN + 1023) / 1024, 1024, 0, stream>>>(counts, partial, bsum);
    scan2_kernel<<<1, 64, 0, stream>>>(bsum, (NN + 1023) / 1024);
    scatter_kernel<<<(NE + 255) / 256, 256, 0, stream>>>(ei, partial, bsum, cursor, cd, ea, epack, relb, eabuf);
    msg_kernel<<<NE / (TPB * 64), 256, 0, stream>>>(xbuf, eabuf, epack, relb, W1p, mb1, W2p, mb2, aggr);
    node_kernel<<<(NN + 63) / 64, 256, 0, stream>>>(xbuf, x, aggr, U1p, ub1, U2p, ub2, gamma, beta, out);
}

// Round 13
// 385.084 us; speedup vs baseline: 2.9011x; 2.9011x over previous
//
#include <hip/hip_runtime.h>

#define NN 50000
#define NE 800000
#define HD 128

typedef short short8 __attribute__((ext_vector_type(8)));
typedef float floatx4 __attribute__((ext_vector_type(4)));

static __device__ __forceinline__ unsigned short f2bf(float f) {
    unsigned int u = __float_as_uint(f);
    unsigned int lsb = (u >> 16) & 1u;
    u += 0x7fffu + lsb;
    return (unsigned short)(u >> 16);
}

// HW packed f32->bf16 (RNE), 2 elems/instr; lo=src0, hi=src1.
static __device__ __forceinline__ short8 pack2(float4 a, float4 b) {
    union { unsigned int u[4]; short8 s; } r;
    asm("v_cvt_pk_bf16_f32 %0, %1, %2" : "=v"(r.u[0]) : "v"(a.x), "v"(a.y));
    asm("v_cvt_pk_bf16_f32 %0, %1, %2" : "=v"(r.u[1]) : "v"(a.z), "v"(a.w));
    asm("v_cvt_pk_bf16_f32 %0, %1, %2" : "=v"(r.u[2]) : "v"(b.x), "v"(b.y));
    asm("v_cvt_pk_bf16_f32 %0, %1, %2" : "=v"(r.u[3]) : "v"(b.z), "v"(b.w));
    return r.s;
}

static __device__ __forceinline__ floatx4 mfma16x16x32(short8 a, short8 b, floatx4 c) {
    asm("v_mfma_f32_16x16x32_bf16 %0, %1, %2, %0" : "+v"(c) : "v"(a), "v"(b));
    return c;
}

// Hazard guards: inline-asm MFMA is invisible to LLVM's GCNHazardRecognizer.
// Ledger: (256,4) + r11 live-state -> 64 VGPR, no scratch. launch_bounds >4
// (r9/r10) and T=4 reg-pipelining (r12) both force allocator spills -> closed.
#define NOPGUARD_INIT8(A) asm volatile("s_nop 3" \
  : "+v"(A[0]),"+v"(A[1]),"+v"(A[2]),"+v"(A[3]),"+v"(A[4]),"+v"(A[5]),"+v"(A[6]),"+v"(A[7]))
#define NOPGUARD8(A) asm volatile("s_nop 7\ns_nop 7" \
  : "+v"(A[0]),"+v"(A[1]),"+v"(A[2]),"+v"(A[3]),"+v"(A[4]),"+v"(A[5]),"+v"(A[6]),"+v"(A[7]))

// Wave-local LDS fence: orders this wave's LDS ops across phases without a
// block barrier (all msg/node LDS handoffs are wave-private 16-row slices).
#define WAVE_LDS_FENCE() asm volatile("s_waitcnt lgkmcnt(0)" ::: "memory")

// ---------------- weight packing (unchanged) ----------------
__global__ void pack_weights(const float* __restrict__ mW1, const float* __restrict__ mW2,
                             const float* __restrict__ uW1, const float* __restrict__ uW2,
                             unsigned short* __restrict__ W1p, unsigned short* __restrict__ W2p,
                             unsigned short* __restrict__ U1p, unsigned short* __restrict__ U2p) {
    int t = blockIdx.x * 256 + threadIdx.x;
    const float* src; unsigned short* dst; int kmax; int i;
    if (t < 40960)        { src = mW1; dst = W1p; kmax = 291; i = t; }
    else if (t < 57344)   { src = mW2; dst = W2p; kmax = 128; i = t - 40960; }
    else if (t < 90112)   { src = uW1; dst = U1p; kmax = 256; i = t - 57344; }
    else if (t < 106496)  { src = uW2; dst = U2p; kmax = 128; i = t - 90112; }
    else return;
    int j = i & 7;
    int lane = (i >> 3) & 63;
    int n = (i >> 9) & 7;
    int kk = i >> 12;
    int k = kk * 32 + ((lane >> 4) << 3) + j;
    int c = n * 16 + (lane & 15);
    float v = (k < kmax) ? src[k * 128 + c] : 0.0f;
    dst[i] = f2bf(v);
}

// ---------------- fp32 -> bf16 cast (x at rest) ----------------
__global__ void cast_kernel(const float* __restrict__ in, unsigned short* __restrict__ out,
                            int n8) {
    int t = blockIdx.x * 256 + threadIdx.x;
    if (t < n8) {
        float4 a = *reinterpret_cast<const float4*>(in + (size_t)t * 8);
        float4 b = *reinterpret_cast<const float4*>(in + (size_t)t * 8 + 4);
        *reinterpret_cast<short8*>(out + (size_t)t * 8) = pack2(a, b);
    }
}

// ---------------- CSR build: hist -> scan -> scatter ----------------
__global__ void hist_kernel(const int* __restrict__ ei, int* __restrict__ counts) {
    int e = blockIdx.x * 256 + threadIdx.x;
    if (e < NE) atomicAdd(&counts[ei[NE + e]], 1);
}

__global__ __launch_bounds__(1024)
void scan1_kernel(const int* __restrict__ counts, int* __restrict__ partial,
                  int* __restrict__ bsum) {
    __shared__ int wsum[16];
    int tid = threadIdx.x;
    int gid = blockIdx.x * 1024 + tid;
    int lane = tid & 63, w = tid >> 6;
    int v = (gid < NN) ? counts[gid] : 0;
    int s = v;
    #pragma unroll
    for (int o = 1; o < 64; o <<= 1) { int t = __shfl_up(s, o); if (lane >= o) s += t; }
    if (lane == 63) wsum[w] = s;
    __syncthreads();
    if (w == 0 && lane < 16) {
        int t = wsum[lane];
        #pragma unroll
        for (int o = 1; o < 16; o <<= 1) { int u = __shfl_up(t, o); if (lane >= o) t += u; }
        wsum[lane] = t;
    }
    __syncthreads();
    int base = (w > 0) ? wsum[w - 1] : 0;
    if (gid < NN) partial[gid] = base + s - v;
    if (tid == 1023) bsum[blockIdx.x] = base + s;
}

__global__ void scan2_kernel(int* __restrict__ bsum, int n) {
    int lane = threadIdx.x;
    int v = (lane < n) ? bsum[lane] : 0;
    int s = v;
    #pragma unroll
    for (int o = 1; o < 64; o <<= 1) { int t = __shfl_up(s, o); if (lane >= o) s += t; }
    if (lane < n) bsum[lane] = s - v;
}

// Writes packed (src | dst<<16), precomputed bf16 rel_coords, AND the bf16
// edge_attr row -- all at the dst-sorted position.
__global__ void scatter_kernel(const int* __restrict__ ei, const int* __restrict__ partial,
                               const int* __restrict__ bsum, int* __restrict__ cursor,
                               const float* __restrict__ cd, const float* __restrict__ ea,
                               unsigned int* __restrict__ epack,
                               uint2* __restrict__ relb,
                               unsigned short* __restrict__ eab) {
    int e = blockIdx.x * 256 + threadIdx.x;
    if (e < NE) {
        int d = ei[NE + e];
        int s = ei[e];
        int pos = partial[d] + bsum[d >> 10] + atomicAdd(&cursor[d], 1);
        epack[pos] = (unsigned int)s | ((unsigned int)d << 16);
        float r0 = cd[d * 3 + 0] - cd[s * 3 + 0];
        float r1 = cd[d * 3 + 1] - cd[s * 3 + 1];
        float r2 = cd[d * 3 + 2] - cd[s * 3 + 2];
        uint2 rr;
        asm("v_cvt_pk_bf16_f32 %0, %1, %2" : "=v"(rr.x) : "v"(r0), "v"(r1));
        asm("v_cvt_pk_bf16_f32 %0, %1, %2" : "=v"(rr.y) : "v"(r2), "v"(0.0f));
        relb[pos] = rr;
        const float* eap = ea + (size_t)e * 32;
        unsigned short* eo = eab + (size_t)pos * 32;
        #pragma unroll
        for (int q = 0; q < 4; ++q) {
            float4 a = *reinterpret_cast<const float4*>(eap + q * 8);
            float4 b = *reinterpret_cast<const float4*>(eap + q * 8 + 4);
            *reinterpret_cast<short8*>(eo + q * 8) = pack2(a, b);
        }
    }
}

// ---------------- message MLP: barrier-free waves + per-wave segmented reduce ----------------
// 64 dst-sorted edges per block, 4 waves. All LDS handoffs are wave-private
// 16-row slices -> NO __syncthreads: waves slip freely, overlapping each
// other's gather/atomic stalls. Wave-local lgkmcnt fences order LDS phases.
__global__ __launch_bounds__(256, 4)
void msg_kernel(const unsigned short* __restrict__ xb, const unsigned short* __restrict__ eab,
                const unsigned int* __restrict__ epack, const uint2* __restrict__ relb,
                const unsigned short* __restrict__ W1p, const float* __restrict__ mb1,
                const unsigned short* __restrict__ W2p, const float* __restrict__ mb2,
                float* __restrict__ aggr) {
    __shared__ unsigned short sH[64 * 136];   // hidden tile, then bf16 out tile
    __shared__ int sDst[64];

    const int tid = threadIdx.x;
    const int lane = tid & 63;
    const int wid = tid >> 6;
    const int g = lane >> 4;
    const int lr = lane & 15;
    const int arow = wid * 16 + lr;          // this lane's edge row (wave-private slice)
    const int e0 = blockIdx.x * 64;

    const unsigned int p = epack[e0 + arow];
    const int src = (int)(p & 0xFFFFu);
    const int dst = (int)(p >> 16);
    if (g == 0) sDst[arow] = dst;            // wave-local write (lanes 0-15 of this wave)

    // 8 x-row gathers + sequential edge-data loads.
    const unsigned short* xs = xb + (size_t)src * 128 + g * 8;
    const unsigned short* xd = xb + (size_t)dst * 128 + g * 8;
    const unsigned short* ep = eab + (size_t)(e0 + arow) * 32 + g * 8;
    const uint2 rr = relb[e0 + arow];

    short8 af[10];
    #pragma unroll
    for (int kk = 0; kk < 4; ++kk) {
        af[kk]     = *reinterpret_cast<const short8*>(xs + kk * 32);
        af[4 + kk] = *reinterpret_cast<const short8*>(xd + kk * 32);
    }
    af[8] = *reinterpret_cast<const short8*>(ep);
    {   // k 288..295: rel (g==0 lanes only; other g cover zero-padded weights)
        union { unsigned int u[4]; short8 s; } a9;
        a9.u[0] = (g == 0) ? rr.x : 0u;
        a9.u[1] = (g == 0) ? rr.y : 0u;
        a9.u[2] = 0u; a9.u[3] = 0u;
        af[9] = a9.s;
    }

    // Layer 1: (64x320) @ (320x128)
    floatx4 acc[8];
    #pragma unroll
    for (int n = 0; n < 8; ++n)
        #pragma unroll
        for (int r = 0; r < 4; ++r) acc[n][r] = 0.0f;
    NOPGUARD_INIT8(acc);

    #pragma unroll
    for (int kk = 0; kk < 10; ++kk) {
        const short8* wb = reinterpret_cast<const short8*>(W1p) + (kk * 8) * 64 + lane;
        #pragma unroll
        for (int n = 0; n < 8; ++n)
            acc[n] = mfma16x16x32(af[kk], wb[n * 64], acc[n]);
    }
    NOPGUARD8(acc);

    // Per-wave segment-head mask over this wave's 16 rows (low 16 bits).
    // sDst written by lanes 0-15 of the SAME wave; in-order wave LDS + fence.
    WAVE_LDS_FENCE();
    unsigned int hm16;
    {
        bool head = false;
        if (lane < 16) {
            int r = wid * 16 + lane;
            head = (lane == 0) || (sDst[r] != sDst[r - 1]);
        }
        unsigned long long m = __ballot(head);
        hm16 = (unsigned int)(m & 0xFFFFull);
    }

    // bias + ReLU -> sH (bf16), wave-private rows
    #pragma unroll
    for (int n = 0; n < 8; ++n) {
        float bias = mb1[n * 16 + lr];
        #pragma unroll
        for (int r = 0; r < 4; ++r) {
            int row = wid * 16 + g * 4 + r;
            sH[row * 136 + n * 16 + lr] = f2bf(fmaxf(acc[n][r] + bias, 0.0f));
        }
    }
    WAVE_LDS_FENCE();

    // Pull layer-2 A fragments (wave-private rows).
    short8 a2[4];
    #pragma unroll
    for (int kk = 0; kk < 4; ++kk)
        a2[kk] = *reinterpret_cast<const short8*>(&sH[arow * 136 + kk * 32 + g * 8]);
    WAVE_LDS_FENCE();   // reads drained before the out-tile overwrites

    // Layer 2: (64x128) @ (128x128)
    floatx4 acc2[8];
    #pragma unroll
    for (int n = 0; n < 8; ++n)
        #pragma unroll
        for (int r = 0; r < 4; ++r) acc2[n][r] = 0.0f;
    NOPGUARD_INIT8(acc2);

    #pragma unroll
    for (int kk = 0; kk < 4; ++kk) {
        const short8* wb = reinterpret_cast<const short8*>(W2p) + (kk * 8) * 64 + lane;
        #pragma unroll
        for (int n = 0; n < 8; ++n)
            acc2[n] = mfma16x16x32(a2[kk], wb[n * 64], acc2[n]);
    }
    NOPGUARD8(acc2);

    // bias -> bf16 LDS out tile (same wave-private rows)
    #pragma unroll
    for (int n = 0; n < 8; ++n) {
        float bias = mb2[n * 16 + lr];
        #pragma unroll
        for (int r = 0; r < 4; ++r) {
            int row = wid * 16 + g * 4 + r;
            sH[row * 136 + n * 16 + lr] = f2bf(acc2[n][r] + bias);
        }
    }
    WAVE_LDS_FENCE();

    // Per-wave bitmask segmented reduce over this wave's 16 rows.
    // Each lane covers cols {lane, lane+64}; one atomic row per segment.
    {
        unsigned int m = hm16;
        while (m) {
            int start = __ffs(m) - 1;
            unsigned int m2 = m & (m - 1);
            int end = m2 ? (__ffs(m2) - 1) : 16;
            float sum0 = 0.0f, sum1 = 0.0f;
            for (int r = start; r < end; ++r) {
                int row = wid * 16 + r;
                unsigned int u0 = sH[row * 136 + lane];
                unsigned int u1 = sH[row * 136 + 64 + lane];
                sum0 += __uint_as_float(u0 << 16);
                sum1 += __uint_as_float(u1 << 16);
            }
            int d = sDst[wid * 16 + start];
            atomicAdd(&aggr[d * 128 + lane], sum0);
            atomicAdd(&aggr[d * 128 + 64 + lane], sum1);
            m = m2;
        }
    }
}

// ---------------- node update MLP + residual + LayerNorm (barrier -> wave fence) ----------------
__global__ __launch_bounds__(256, 4)
void node_kernel(const unsigned short* __restrict__ xb, const float* __restrict__ x,
                 const float* __restrict__ aggr,
                 const unsigned short* __restrict__ U1p, const float* __restrict__ ub1,
                 const unsigned short* __restrict__ U2p, const float* __restrict__ ub2,
                 const float* __restrict__ gamma, const float* __restrict__ beta,
                 float* __restrict__ out) {
    __shared__ unsigned short sH[64 * 136];

    const int tid = threadIdx.x;
    const int lane = tid & 63;
    const int wid = tid >> 6;
    const int g = lane >> 4;
    const int lr = lane & 15;
    const int arow = wid * 16 + lr;
    const int n0 = blockIdx.x * 64;

    int nd0 = n0 + arow;
    int ndc0 = (nd0 < NN) ? nd0 : (NN - 1);

    const unsigned short* xp = xb + (size_t)ndc0 * 128 + g * 8;
    const float* ap = aggr + (size_t)ndc0 * 128 + g * 8;

    short8 af[8];
    float4 ta[8];
    #pragma unroll
    for (int kk = 0; kk < 4; ++kk) {
        af[kk] = *reinterpret_cast<const short8*>(xp + kk * 32);
        ta[2 * kk]     = *reinterpret_cast<const float4*>(ap + kk * 32);
        ta[2 * kk + 1] = *reinterpret_cast<const float4*>(ap + kk * 32 + 4);
    }
    #pragma unroll
    for (int kk = 0; kk < 4; ++kk)
        af[4 + kk] = pack2(ta[2 * kk], ta[2 * kk + 1]);

    // Layer 1: (64x256) @ (256x128)
    floatx4 acc[8];
    #pragma unroll
    for (int n = 0; n < 8; ++n)
        #pragma unroll
        for (int r = 0; r < 4; ++r) acc[n][r] = 0.0f;
    NOPGUARD_INIT8(acc);

    #pragma unroll
    for (int kk = 0; kk < 8; ++kk) {
        const short8* wb = reinterpret_cast<const short8*>(U1p) + (kk * 8) * 64 + lane;
        #pragma unroll
        for (int n = 0; n < 8; ++n)
            acc[n] = mfma16x16x32(af[kk], wb[n * 64], acc[n]);
    }
    NOPGUARD8(acc);

    #pragma unroll
    for (int n = 0; n < 8; ++n) {
        float bias = ub1[n * 16 + lr];
        #pragma unroll
        for (int r = 0; r < 4; ++r) {
            int row = wid * 16 + g * 4 + r;
            sH[row * 136 + n * 16 + lr] = f2bf(fmaxf(acc[n][r] + bias, 0.0f));
        }
    }
    WAVE_LDS_FENCE();   // wave-private handoff: no block barrier needed

    short8 a2[4];
    #pragma unroll
    for (int kk = 0; kk < 4; ++kk)
        a2[kk] = *reinterpret_cast<const short8*>(&sH[arow * 136 + kk * 32 + g * 8]);

    // Layer 2: (64x128) @ (128x128)
    floatx4 acc2[8];
    #pragma unroll
    for (int n = 0; n < 8; ++n)
        #pragma unroll
        for (int r = 0; r < 4; ++r) acc2[n][r] = 0.0f;
    NOPGUARD_INIT8(acc2);

    #pragma unroll
    for (int kk = 0; kk < 4; ++kk) {
        const short8* wb = reinterpret_cast<const short8*>(U2p) + (kk * 8) * 64 + lane;
        #pragma unroll
        for (int n = 0; n < 8; ++n)
            acc2[n] = mfma16x16x32(a2[kk], wb[n * 64], acc2[n]);
    }
    NOPGUARD8(acc2);

    // Epilogue: residual + LayerNorm in registers (16-lane shfl_xor row-reduce).
    #pragma unroll
    for (int r = 0; r < 4; ++r) {
        int row = wid * 16 + g * 4 + r;
        int nd = n0 + row;
        int ndc = (nd < NN) ? nd : (NN - 1);
        float vals[8];
        float s1 = 0.0f, s2 = 0.0f;
        #pragma unroll
        for (int n = 0; n < 8; ++n) {
            int col = n * 16 + lr;
            float v = acc2[n][r] + ub2[col] + x[ndc * 128 + col];
            vals[n] = v;
            s1 += v;
            s2 += v * v;
        }
        #pragma unroll
        for (int m = 1; m < 16; m <<= 1) {
            s1 += __shfl_xor(s1, m);
            s2 += __shfl_xor(s2, m);
        }
        float mean = s1 * (1.0f / 128.0f);
        float var = s2 * (1.0f / 128.0f) - mean * mean;
        float inv = rsqrtf(var + 1e-5f);
        if (nd < NN) {
            #pragma unroll
            for (int n = 0; n < 8; ++n) {
                int col = n * 16 + lr;
                out[nd * 128 + col] = (vals[n] - mean) * inv * gamma[col] + beta[col];
            }
        }
    }
}

extern "C" void kernel_launch(void* const* d_in, const int* in_sizes, int n_in,
                              void* d_out, int out_size, void* d_ws, size_t ws_size,
                              hipStream_t stream) {
    const float* x     = (const float*)d_in[0];
    const int*   ei    = (const int*)d_in[1];
    const float* ea    = (const float*)d_in[2];
    const float* cd    = (const float*)d_in[3];
    const float* mW1   = (const float*)d_in[4];
    const float* mb1   = (const float*)d_in[5];
    const float* mW2   = (const float*)d_in[6];
    const float* mb2   = (const float*)d_in[7];
    const float* uW1   = (const float*)d_in[8];
    const float* ub1   = (const float*)d_in[9];
    const float* uW2   = (const float*)d_in[10];
    const float* ub2   = (const float*)d_in[11];
    const float* gamma = (const float*)d_in[12];
    const float* beta  = (const float*)d_in[13];
    float* out = (float*)d_out;

    char* ws = (char*)d_ws;
    unsigned short* W1p = (unsigned short*)(ws);                     // 81,920 B
    unsigned short* W2p = (unsigned short*)(ws + 81920);             // 32,768 B
    unsigned short* U1p = (unsigned short*)(ws + 114688);            // 65,536 B
    unsigned short* U2p = (unsigned short*)(ws + 180224);            // 32,768 B
    int* counts  = (int*)(ws + 212992);                              // 200,704 B
    int* cursor  = (int*)(ws + 413696);                              // 200,704 B (adjacent: one memset)
    int* partial = (int*)(ws + 614400);                              // 200,704 B
    int* bsum    = (int*)(ws + 815104);                              // 256 B
    unsigned int* epack = (unsigned int*)(ws + 815360);              // 3,200,000 B
    uint2* relb  = (uint2*)(ws + 4015360);                           // 6,400,000 B
    unsigned short* xbuf = (unsigned short*)(ws + 10415360);         // 12,800,000 B
    unsigned short* eabuf = (unsigned short*)(ws + 23215360);        // 51,200,000 B
    // total ws use: 74,415,360 B

    float* aggr = out;   // aggr lives in d_out (exactly NN*HD floats)

    hipMemsetAsync(counts, 0, (size_t)(614400 - 212992), stream);
    hipMemsetAsync(aggr, 0, (size_t)NN * HD * sizeof(float), stream);

    pack_weights<<<416, 256, 0, stream>>>(mW1, mW2, uW1, uW2, W1p, W2p, U1p, U2p);
    cast_kernel<<<(NN * HD / 8 + 255) / 256, 256, 0, stream>>>(x, xbuf, NN * HD / 8);
    hist_kernel<<<(NE + 255) / 256, 256, 0, stream>>>(ei, counts);
    scan1_kernel<<<(NN + 1023) / 1024, 1024, 0, stream>>>(counts, partial, bsum);
    scan2_kernel<<<1, 64, 0, stream>>>(bsum, (NN + 1023) / 1024);
    scatter_kernel<<<(NE + 255) / 256, 256, 0, stream>>>(ei, partial, bsum, cursor, cd, ea, epack, relb, eabuf);
    msg_kernel<<<NE / 64, 256, 0, stream>>>(xbuf, eabuf, epack, relb, W1p, mb1, W2p, mb2, aggr);
    node_kernel<<<(NN + 63) / 64, 256, 0, stream>>>(xbuf, x, aggr, U1p, ub1, U2p, ub2, gamma, beta, out);
}

// Round 14
// 366.440 us; speedup vs baseline: 3.0487x; 1.0509x over previous
//
#include <hip/hip_runtime.h>

#define NN 50000
#define NE 800000
#define HD 128

typedef short short8 __attribute__((ext_vector_type(8)));
typedef float floatx4 __attribute__((ext_vector_type(4)));

static __device__ __forceinline__ unsigned short f2bf(float f) {
    unsigned int u = __float_as_uint(f);
    unsigned int lsb = (u >> 16) & 1u;
    u += 0x7fffu + lsb;
    return (unsigned short)(u >> 16);
}

// HW packed f32->bf16 (RNE), 2 elems/instr; lo=src0, hi=src1.
static __device__ __forceinline__ short8 pack2(float4 a, float4 b) {
    union { unsigned int u[4]; short8 s; } r;
    asm("v_cvt_pk_bf16_f32 %0, %1, %2" : "=v"(r.u[0]) : "v"(a.x), "v"(a.y));
    asm("v_cvt_pk_bf16_f32 %0, %1, %2" : "=v"(r.u[1]) : "v"(a.z), "v"(a.w));
    asm("v_cvt_pk_bf16_f32 %0, %1, %2" : "=v"(r.u[2]) : "v"(b.x), "v"(b.y));
    asm("v_cvt_pk_bf16_f32 %0, %1, %2" : "=v"(r.u[3]) : "v"(b.z), "v"(b.w));
    return r.s;
}

static __device__ __forceinline__ floatx4 mfma16x16x32(short8 a, short8 b, floatx4 c) {
    asm("v_mfma_f32_16x16x32_bf16 %0, %1, %2, %0" : "+v"(c) : "v"(a), "v"(b));
    return c;
}

// Hazard guards: inline-asm MFMA is invisible to LLVM's GCNHazardRecognizer.
// Ledger: launch_bounds attr caps occupancy at its value (2->23%, 4->43%,
// 8->85%) but attr>4 forces sub-natural register allocations + scratch
// (r9/r10). This round: NO launch_bounds -- default flat-work-group-size
// 1,1024 gives the same 128-VGPR budget as (256,4) without the occupancy cap.
#define NOPGUARD_INIT8(A) asm volatile("s_nop 3" \
  : "+v"(A[0]),"+v"(A[1]),"+v"(A[2]),"+v"(A[3]),"+v"(A[4]),"+v"(A[5]),"+v"(A[6]),"+v"(A[7]))
#define NOPGUARD8(A) asm volatile("s_nop 7\ns_nop 7" \
  : "+v"(A[0]),"+v"(A[1]),"+v"(A[2]),"+v"(A[3]),"+v"(A[4]),"+v"(A[5]),"+v"(A[6]),"+v"(A[7]))

// Wave-local LDS fence: orders this wave's LDS ops across phases without a
// block barrier (all msg/node LDS handoffs are wave-private 16-row slices).
#define WAVE_LDS_FENCE() asm volatile("s_waitcnt lgkmcnt(0)" ::: "memory")

// ---------------- weight packing (unchanged) ----------------
__global__ void pack_weights(const float* __restrict__ mW1, const float* __restrict__ mW2,
                             const float* __restrict__ uW1, const float* __restrict__ uW2,
                             unsigned short* __restrict__ W1p, unsigned short* __restrict__ W2p,
                             unsigned short* __restrict__ U1p, unsigned short* __restrict__ U2p) {
    int t = blockIdx.x * 256 + threadIdx.x;
    const float* src; unsigned short* dst; int kmax; int i;
    if (t < 40960)        { src = mW1; dst = W1p; kmax = 291; i = t; }
    else if (t < 57344)   { src = mW2; dst = W2p; kmax = 128; i = t - 40960; }
    else if (t < 90112)   { src = uW1; dst = U1p; kmax = 256; i = t - 57344; }
    else if (t < 106496)  { src = uW2; dst = U2p; kmax = 128; i = t - 90112; }
    else return;
    int j = i & 7;
    int lane = (i >> 3) & 63;
    int n = (i >> 9) & 7;
    int kk = i >> 12;
    int k = kk * 32 + ((lane >> 4) << 3) + j;
    int c = n * 16 + (lane & 15);
    float v = (k < kmax) ? src[k * 128 + c] : 0.0f;
    dst[i] = f2bf(v);
}

// ---------------- fp32 -> bf16 cast (x at rest) ----------------
__global__ void cast_kernel(const float* __restrict__ in, unsigned short* __restrict__ out,
                            int n8) {
    int t = blockIdx.x * 256 + threadIdx.x;
    if (t < n8) {
        float4 a = *reinterpret_cast<const float4*>(in + (size_t)t * 8);
        float4 b = *reinterpret_cast<const float4*>(in + (size_t)t * 8 + 4);
        *reinterpret_cast<short8*>(out + (size_t)t * 8) = pack2(a, b);
    }
}

// ---------------- CSR build: hist -> scan -> scatter ----------------
__global__ void hist_kernel(const int* __restrict__ ei, int* __restrict__ counts) {
    int e = blockIdx.x * 256 + threadIdx.x;
    if (e < NE) atomicAdd(&counts[ei[NE + e]], 1);
}

__global__ __launch_bounds__(1024)
void scan1_kernel(const int* __restrict__ counts, int* __restrict__ partial,
                  int* __restrict__ bsum) {
    __shared__ int wsum[16];
    int tid = threadIdx.x;
    int gid = blockIdx.x * 1024 + tid;
    int lane = tid & 63, w = tid >> 6;
    int v = (gid < NN) ? counts[gid] : 0;
    int s = v;
    #pragma unroll
    for (int o = 1; o < 64; o <<= 1) { int t = __shfl_up(s, o); if (lane >= o) s += t; }
    if (lane == 63) wsum[w] = s;
    __syncthreads();
    if (w == 0 && lane < 16) {
        int t = wsum[lane];
        #pragma unroll
        for (int o = 1; o < 16; o <<= 1) { int u = __shfl_up(t, o); if (lane >= o) t += u; }
        wsum[lane] = t;
    }
    __syncthreads();
    int base = (w > 0) ? wsum[w - 1] : 0;
    if (gid < NN) partial[gid] = base + s - v;
    if (tid == 1023) bsum[blockIdx.x] = base + s;
}

__global__ void scan2_kernel(int* __restrict__ bsum, int n) {
    int lane = threadIdx.x;
    int v = (lane < n) ? bsum[lane] : 0;
    int s = v;
    #pragma unroll
    for (int o = 1; o < 64; o <<= 1) { int t = __shfl_up(s, o); if (lane >= o) s += t; }
    if (lane < n) bsum[lane] = s - v;
}

// Writes packed (src | dst<<16), precomputed bf16 rel_coords, AND the bf16
// edge_attr row -- all at the dst-sorted position.
__global__ void scatter_kernel(const int* __restrict__ ei, const int* __restrict__ partial,
                               const int* __restrict__ bsum, int* __restrict__ cursor,
                               const float* __restrict__ cd, const float* __restrict__ ea,
                               unsigned int* __restrict__ epack,
                               uint2* __restrict__ relb,
                               unsigned short* __restrict__ eab) {
    int e = blockIdx.x * 256 + threadIdx.x;
    if (e < NE) {
        int d = ei[NE + e];
        int s = ei[e];
        int pos = partial[d] + bsum[d >> 10] + atomicAdd(&cursor[d], 1);
        epack[pos] = (unsigned int)s | ((unsigned int)d << 16);
        float r0 = cd[d * 3 + 0] - cd[s * 3 + 0];
        float r1 = cd[d * 3 + 1] - cd[s * 3 + 1];
        float r2 = cd[d * 3 + 2] - cd[s * 3 + 2];
        uint2 rr;
        asm("v_cvt_pk_bf16_f32 %0, %1, %2" : "=v"(rr.x) : "v"(r0), "v"(r1));
        asm("v_cvt_pk_bf16_f32 %0, %1, %2" : "=v"(rr.y) : "v"(r2), "v"(0.0f));
        relb[pos] = rr;
        const float* eap = ea + (size_t)e * 32;
        unsigned short* eo = eab + (size_t)pos * 32;
        #pragma unroll
        for (int q = 0; q < 4; ++q) {
            float4 a = *reinterpret_cast<const float4*>(eap + q * 8);
            float4 b = *reinterpret_cast<const float4*>(eap + q * 8 + 4);
            *reinterpret_cast<short8*>(eo + q * 8) = pack2(a, b);
        }
    }
}

// ---------------- message MLP: barrier-free waves, NO launch_bounds ----------------
// 64 dst-sorted edges per block, 4 waves. Wave-private LDS slices, no block
// barriers. No launch_bounds: same 128-VGPR default budget as (256,4), but
// without the waves-per-eu occupancy cap -> scheduler packs to LDS/VGPR
// limits (8 blocks/CU at 17.9 KB LDS, 64 VGPR).
__global__
void msg_kernel(const unsigned short* __restrict__ xb, const unsigned short* __restrict__ eab,
                const unsigned int* __restrict__ epack, const uint2* __restrict__ relb,
                const unsigned short* __restrict__ W1p, const float* __restrict__ mb1,
                const unsigned short* __restrict__ W2p, const float* __restrict__ mb2,
                float* __restrict__ aggr) {
    __shared__ unsigned short sH[64 * 136];   // hidden tile, then bf16 out tile
    __shared__ int sDst[64];

    const int tid = threadIdx.x;
    const int lane = tid & 63;
    const int wid = tid >> 6;
    const int g = lane >> 4;
    const int lr = lane & 15;
    const int arow = wid * 16 + lr;          // this lane's edge row (wave-private slice)
    const int e0 = blockIdx.x * 64;

    const unsigned int p = epack[e0 + arow];
    const int src = (int)(p & 0xFFFFu);
    const int dst = (int)(p >> 16);
    if (g == 0) sDst[arow] = dst;            // wave-local write (lanes 0-15 of this wave)

    // 8 x-row gathers + sequential edge-data loads.
    const unsigned short* xs = xb + (size_t)src * 128 + g * 8;
    const unsigned short* xd = xb + (size_t)dst * 128 + g * 8;
    const unsigned short* ep = eab + (size_t)(e0 + arow) * 32 + g * 8;
    const uint2 rr = relb[e0 + arow];

    short8 af[10];
    #pragma unroll
    for (int kk = 0; kk < 4; ++kk) {
        af[kk]     = *reinterpret_cast<const short8*>(xs + kk * 32);
        af[4 + kk] = *reinterpret_cast<const short8*>(xd + kk * 32);
    }
    af[8] = *reinterpret_cast<const short8*>(ep);
    {   // k 288..295: rel (g==0 lanes only; other g cover zero-padded weights)
        union { unsigned int u[4]; short8 s; } a9;
        a9.u[0] = (g == 0) ? rr.x : 0u;
        a9.u[1] = (g == 0) ? rr.y : 0u;
        a9.u[2] = 0u; a9.u[3] = 0u;
        af[9] = a9.s;
    }

    // Layer 1: (64x320) @ (320x128)
    floatx4 acc[8];
    #pragma unroll
    for (int n = 0; n < 8; ++n)
        #pragma unroll
        for (int r = 0; r < 4; ++r) acc[n][r] = 0.0f;
    NOPGUARD_INIT8(acc);

    #pragma unroll
    for (int kk = 0; kk < 10; ++kk) {
        const short8* wb = reinterpret_cast<const short8*>(W1p) + (kk * 8) * 64 + lane;
        #pragma unroll
        for (int n = 0; n < 8; ++n)
            acc[n] = mfma16x16x32(af[kk], wb[n * 64], acc[n]);
    }
    NOPGUARD8(acc);

    // Per-wave segment-head mask over this wave's 16 rows (low 16 bits).
    WAVE_LDS_FENCE();
    unsigned int hm16;
    {
        bool head = false;
        if (lane < 16) {
            int r = wid * 16 + lane;
            head = (lane == 0) || (sDst[r] != sDst[r - 1]);
        }
        unsigned long long m = __ballot(head);
        hm16 = (unsigned int)(m & 0xFFFFull);
    }

    // bias + ReLU -> sH (bf16), wave-private rows
    #pragma unroll
    for (int n = 0; n < 8; ++n) {
        float bias = mb1[n * 16 + lr];
        #pragma unroll
        for (int r = 0; r < 4; ++r) {
            int row = wid * 16 + g * 4 + r;
            sH[row * 136 + n * 16 + lr] = f2bf(fmaxf(acc[n][r] + bias, 0.0f));
        }
    }
    WAVE_LDS_FENCE();

    // Pull layer-2 A fragments (wave-private rows).
    short8 a2[4];
    #pragma unroll
    for (int kk = 0; kk < 4; ++kk)
        a2[kk] = *reinterpret_cast<const short8*>(&sH[arow * 136 + kk * 32 + g * 8]);
    WAVE_LDS_FENCE();   // reads drained before the out-tile overwrites

    // Layer 2: (64x128) @ (128x128)
    floatx4 acc2[8];
    #pragma unroll
    for (int n = 0; n < 8; ++n)
        #pragma unroll
        for (int r = 0; r < 4; ++r) acc2[n][r] = 0.0f;
    NOPGUARD_INIT8(acc2);

    #pragma unroll
    for (int kk = 0; kk < 4; ++kk) {
        const short8* wb = reinterpret_cast<const short8*>(W2p) + (kk * 8) * 64 + lane;
        #pragma unroll
        for (int n = 0; n < 8; ++n)
            acc2[n] = mfma16x16x32(a2[kk], wb[n * 64], acc2[n]);
    }
    NOPGUARD8(acc2);

    // bias -> bf16 LDS out tile (same wave-private rows)
    #pragma unroll
    for (int n = 0; n < 8; ++n) {
        float bias = mb2[n * 16 + lr];
        #pragma unroll
        for (int r = 0; r < 4; ++r) {
            int row = wid * 16 + g * 4 + r;
            sH[row * 136 + n * 16 + lr] = f2bf(acc2[n][r] + bias);
        }
    }
    WAVE_LDS_FENCE();

    // Per-wave bitmask segmented reduce over this wave's 16 rows.
    // Each lane covers cols {lane, lane+64}; one atomic row per segment.
    {
        unsigned int m = hm16;
        while (m) {
            int start = __ffs(m) - 1;
            unsigned int m2 = m & (m - 1);
            int end = m2 ? (__ffs(m2) - 1) : 16;
            float sum0 = 0.0f, sum1 = 0.0f;
            for (int r = start; r < end; ++r) {
                int row = wid * 16 + r;
                unsigned int u0 = sH[row * 136 + lane];
                unsigned int u1 = sH[row * 136 + 64 + lane];
                sum0 += __uint_as_float(u0 << 16);
                sum1 += __uint_as_float(u1 << 16);
            }
            int d = sDst[wid * 16 + start];
            atomicAdd(&aggr[d * 128 + lane], sum0);
            atomicAdd(&aggr[d * 128 + 64 + lane], sum1);
            m = m2;
        }
    }
}

// ---------------- node update MLP + residual + LayerNorm (no launch_bounds) ----------------
__global__
void node_kernel(const unsigned short* __restrict__ xb, const float* __restrict__ x,
                 const float* __restrict__ aggr,
                 const unsigned short* __restrict__ U1p, const float* __restrict__ ub1,
                 const unsigned short* __restrict__ U2p, const float* __restrict__ ub2,
                 const float* __restrict__ gamma, const float* __restrict__ beta,
                 float* __restrict__ out) {
    __shared__ unsigned short sH[64 * 136];

    const int tid = threadIdx.x;
    const int lane = tid & 63;
    const int wid = tid >> 6;
    const int g = lane >> 4;
    const int lr = lane & 15;
    const int arow = wid * 16 + lr;
    const int n0 = blockIdx.x * 64;

    int nd0 = n0 + arow;
    int ndc0 = (nd0 < NN) ? nd0 : (NN - 1);

    const unsigned short* xp = xb + (size_t)ndc0 * 128 + g * 8;
    const float* ap = aggr + (size_t)ndc0 * 128 + g * 8;

    short8 af[8];
    float4 ta[8];
    #pragma unroll
    for (int kk = 0; kk < 4; ++kk) {
        af[kk] = *reinterpret_cast<const short8*>(xp + kk * 32);
        ta[2 * kk]     = *reinterpret_cast<const float4*>(ap + kk * 32);
        ta[2 * kk + 1] = *reinterpret_cast<const float4*>(ap + kk * 32 + 4);
    }
    #pragma unroll
    for (int kk = 0; kk < 4; ++kk)
        af[4 + kk] = pack2(ta[2 * kk], ta[2 * kk + 1]);

    // Layer 1: (64x256) @ (256x128)
    floatx4 acc[8];
    #pragma unroll
    for (int n = 0; n < 8; ++n)
        #pragma unroll
        for (int r = 0; r < 4; ++r) acc[n][r] = 0.0f;
    NOPGUARD_INIT8(acc);

    #pragma unroll
    for (int kk = 0; kk < 8; ++kk) {
        const short8* wb = reinterpret_cast<const short8*>(U1p) + (kk * 8) * 64 + lane;
        #pragma unroll
        for (int n = 0; n < 8; ++n)
            acc[n] = mfma16x16x32(af[kk], wb[n * 64], acc[n]);
    }
    NOPGUARD8(acc);

    #pragma unroll
    for (int n = 0; n < 8; ++n) {
        float bias = ub1[n * 16 + lr];
        #pragma unroll
        for (int r = 0; r < 4; ++r) {
            int row = wid * 16 + g * 4 + r;
            sH[row * 136 + n * 16 + lr] = f2bf(fmaxf(acc[n][r] + bias, 0.0f));
        }
    }
    WAVE_LDS_FENCE();   // wave-private handoff: no block barrier needed

    short8 a2[4];
    #pragma unroll
    for (int kk = 0; kk < 4; ++kk)
        a2[kk] = *reinterpret_cast<const short8*>(&sH[arow * 136 + kk * 32 + g * 8]);

    // Layer 2: (64x128) @ (128x128)
    floatx4 acc2[8];
    #pragma unroll
    for (int n = 0; n < 8; ++n)
        #pragma unroll
        for (int r = 0; r < 4; ++r) acc2[n][r] = 0.0f;
    NOPGUARD_INIT8(acc2);

    #pragma unroll
    for (int kk = 0; kk < 4; ++kk) {
        const short8* wb = reinterpret_cast<const short8*>(U2p) + (kk * 8) * 64 + lane;
        #pragma unroll
        for (int n = 0; n < 8; ++n)
            acc2[n] = mfma16x16x32(a2[kk], wb[n * 64], acc2[n]);
    }
    NOPGUARD8(acc2);

    // Epilogue: residual + LayerNorm in registers (16-lane shfl_xor row-reduce).
    #pragma unroll
    for (int r = 0; r < 4; ++r) {
        int row = wid * 16 + g * 4 + r;
        int nd = n0 + row;
        int ndc = (nd < NN) ? nd : (NN - 1);
        float vals[8];
        float s1 = 0.0f, s2 = 0.0f;
        #pragma unroll
        for (int n = 0; n < 8; ++n) {
            int col = n * 16 + lr;
            float v = acc2[n][r] + ub2[col] + x[ndc * 128 + col];
            vals[n] = v;
            s1 += v;
            s2 += v * v;
        }
        #pragma unroll
        for (int m = 1; m < 16; m <<= 1) {
            s1 += __shfl_xor(s1, m);
            s2 += __shfl_xor(s2, m);
        }
        float mean = s1 * (1.0f / 128.0f);
        float var = s2 * (1.0f / 128.0f) - mean * mean;
        float inv = rsqrtf(var + 1e-5f);
        if (nd < NN) {
            #pragma unroll
            for (int n = 0; n < 8; ++n) {
                int col = n * 16 + lr;
                out[nd * 128 + col] = (vals[n] - mean) * inv * gamma[col] + beta[col];
            }
        }
    }
}

extern "C" void kernel_launch(void* const* d_in, const int* in_sizes, int n_in,
                              void* d_out, int out_size, void* d_ws, size_t ws_size,
                              hipStream_t stream) {
    const float* x     = (const float*)d_in[0];
    const int*   ei    = (const int*)d_in[1];
    const float* ea    = (const float*)d_in[2];
    const float* cd    = (const float*)d_in[3];
    const float* mW1   = (const float*)d_in[4];
    const float* mb1   = (const float*)d_in[5];
    const float* mW2   = (const float*)d_in[6];
    const float* mb2   = (const float*)d_in[7];
    const float* uW1   = (const float*)d_in[8];
    const float* ub1   = (const float*)d_in[9];
    const float* uW2   = (const float*)d_in[10];
    const float* ub2   = (const float*)d_in[11];
    const float* gamma = (const float*)d_in[12];
    const float* beta  = (const float*)d_in[13];
    float* out = (float*)d_out;

    char* ws = (char*)d_ws;
    unsigned short* W1p = (unsigned short*)(ws);                     // 81,920 B
    unsigned short* W2p = (unsigned short*)(ws + 81920);             // 32,768 B
    unsigned short* U1p = (unsigned short*)(ws + 114688);            // 65,536 B
    unsigned short* U2p = (unsigned short*)(ws + 180224);            // 32,768 B
    int* counts  = (int*)(ws + 212992);                              // 200,704 B
    int* cursor  = (int*)(ws + 413696);                              // 200,704 B (adjacent: one memset)
    int* partial = (int*)(ws + 614400);                              // 200,704 B
    int* bsum    = (int*)(ws + 815104);                              // 256 B
    unsigned int* epack = (unsigned int*)(ws + 815360);              // 3,200,000 B
    uint2* relb  = (uint2*)(ws + 4015360);                           // 6,400,000 B
    unsigned short* xbuf = (unsigned short*)(ws + 10415360);         // 12,800,000 B
    unsigned short* eabuf = (unsigned short*)(ws + 23215360);        // 51,200,000 B
    // total ws use: 74,415,360 B

    float* aggr = out;   // aggr lives in d_out (exactly NN*HD floats)

    hipMemsetAsync(counts, 0, (size_t)(614400 - 212992), stream);
    hipMemsetAsync(aggr, 0, (size_t)NN * HD * sizeof(float), stream);

    pack_weights<<<416, 256, 0, stream>>>(mW1, mW2, uW1, uW2, W1p, W2p, U1p, U2p);
    cast_kernel<<<(NN * HD / 8 + 255) / 256, 256, 0, stream>>>(x, xbuf, NN * HD / 8);
    hist_kernel<<<(NE + 255) / 256, 256, 0, stream>>>(ei, counts);
    scan1_kernel<<<(NN + 1023) / 1024, 1024, 0, stream>>>(counts, partial, bsum);
    scan2_kernel<<<1, 64, 0, stream>>>(bsum, (NN + 1023) / 1024);
    scatter_kernel<<<(NE + 255) / 256, 256, 0, stream>>>(ei, partial, bsum, cursor, cd, ea, epack, relb, eabuf);
    msg_kernel<<<NE / 64, 256, 0, stream>>>(xbuf, eabuf, epack, relb, W1p, mb1, W2p, mb2, aggr);
    node_kernel<<<(NN + 63) / 64, 256, 0, stream>>>(xbuf, x, aggr, U1p, ub1, U2p, ub2, gamma, beta, out);
}

// Round 15
// 285.478 us; speedup vs baseline: 3.9134x; 1.2836x over previous
//
#include <hip/hip_runtime.h>

#define NN 50000
#define NE 800000
#define HD 128

typedef short short8 __attribute__((ext_vector_type(8)));
typedef float floatx4 __attribute__((ext_vector_type(4)));
typedef float floatx16 __attribute__((ext_vector_type(16)));

static __device__ __forceinline__ unsigned short f2bf(float f) {
    unsigned int u = __float_as_uint(f);
    unsigned int lsb = (u >> 16) & 1u;
    u += 0x7fffu + lsb;
    return (unsigned short)(u >> 16);
}

// HW packed f32->bf16 (RNE), 2 elems/instr; lo=src0, hi=src1.
static __device__ __forceinline__ short8 pack2(float4 a, float4 b) {
    union { unsigned int u[4]; short8 s; } r;
    asm("v_cvt_pk_bf16_f32 %0, %1, %2" : "=v"(r.u[0]) : "v"(a.x), "v"(a.y));
    asm("v_cvt_pk_bf16_f32 %0, %1, %2" : "=v"(r.u[1]) : "v"(a.z), "v"(a.w));
    asm("v_cvt_pk_bf16_f32 %0, %1, %2" : "=v"(r.u[2]) : "v"(b.x), "v"(b.y));
    asm("v_cvt_pk_bf16_f32 %0, %1, %2" : "=v"(r.u[3]) : "v"(b.z), "v"(b.w));
    return r.s;
}

static __device__ __forceinline__ floatx4 mfma16x16x32(short8 a, short8 b, floatx4 c) {
    asm("v_mfma_f32_16x16x32_bf16 %0, %1, %2, %0" : "+v"(c) : "v"(a), "v"(b));
    return c;
}

static __device__ __forceinline__ floatx16 mfma32x32x16(short8 a, short8 b, floatx16 c) {
    asm("v_mfma_f32_32x32x16_bf16 %0, %1, %2, %0" : "+v"(c) : "v"(a), "v"(b));
    return c;
}

// Hazard guards: inline-asm MFMA is invisible to LLVM's GCNHazardRecognizer.
// 16x16 (4-pass) guards:
#define NOPGUARD_INIT8(A) asm volatile("s_nop 3" \
  : "+v"(A[0]),"+v"(A[1]),"+v"(A[2]),"+v"(A[3]),"+v"(A[4]),"+v"(A[5]),"+v"(A[6]),"+v"(A[7]))
#define NOPGUARD8(A) asm volatile("s_nop 7\ns_nop 7" \
  : "+v"(A[0]),"+v"(A[1]),"+v"(A[2]),"+v"(A[3]),"+v"(A[4]),"+v"(A[5]),"+v"(A[6]),"+v"(A[7]))
// 32x32 (16-pass) guards: larger wait-state requirements.
#define NOPGUARD_INIT4x16(A) asm volatile("s_nop 7" \
  : "+v"(A[0]),"+v"(A[1]),"+v"(A[2]),"+v"(A[3]))
#define NOPGUARD4x16(A) asm volatile("s_nop 7\ns_nop 7\ns_nop 7" \
  : "+v"(A[0]),"+v"(A[1]),"+v"(A[2]),"+v"(A[3]))

// Wave-local LDS fence.
#define WAVE_LDS_FENCE() asm volatile("s_waitcnt lgkmcnt(0)" ::: "memory")

// ---------------- weight packing ----------------
// W1q/W2q (msg, 32x32x16 B-layout): idx=((s*4+n)*64+lane)*8+j <-> k=s*16+(lane>>5)*8+j, c=n*32+(lane&31)
// U1p/U2p (node, 16x16x32 B-layout): idx=((kk*8+n)*64+lane)*8+j <-> k=kk*32+(lane>>4)*8+j, c=n*16+(lane&15)
__global__ void pack_weights(const float* __restrict__ mW1, const float* __restrict__ mW2,
                             const float* __restrict__ uW1, const float* __restrict__ uW2,
                             unsigned short* __restrict__ W1q, unsigned short* __restrict__ W2q,
                             unsigned short* __restrict__ U1p, unsigned short* __restrict__ U2p) {
    int t = blockIdx.x * 256 + threadIdx.x;
    if (t < 40960) {
        int i = t;
        int j = i & 7, lane = (i >> 3) & 63, n = (i >> 9) & 3, s = i >> 11;
        int k = s * 16 + ((lane >> 5) << 3) + j;
        int c = n * 32 + (lane & 31);
        W1q[i] = f2bf((k < 291) ? mW1[k * 128 + c] : 0.0f);
    } else if (t < 57344) {
        int i = t - 40960;
        int j = i & 7, lane = (i >> 3) & 63, n = (i >> 9) & 3, s = i >> 11;
        int k = s * 16 + ((lane >> 5) << 3) + j;
        int c = n * 32 + (lane & 31);
        W2q[i] = f2bf(mW2[k * 128 + c]);
    } else if (t < 90112) {
        int i = t - 57344;
        int j = i & 7, lane = (i >> 3) & 63, n = (i >> 9) & 7, kk = i >> 12;
        int k = kk * 32 + ((lane >> 4) << 3) + j;
        int c = n * 16 + (lane & 15);
        U1p[i] = f2bf(uW1[k * 128 + c]);
    } else if (t < 106496) {
        int i = t - 90112;
        int j = i & 7, lane = (i >> 3) & 63, n = (i >> 9) & 7, kk = i >> 12;
        int k = kk * 32 + ((lane >> 4) << 3) + j;
        int c = n * 16 + (lane & 15);
        U2p[i] = f2bf(uW2[k * 128 + c]);
    }
}

// ---------------- fp32 -> bf16 cast (x at rest) ----------------
__global__ void cast_kernel(const float* __restrict__ in, unsigned short* __restrict__ out,
                            int n8) {
    int t = blockIdx.x * 256 + threadIdx.x;
    if (t < n8) {
        float4 a = *reinterpret_cast<const float4*>(in + (size_t)t * 8);
        float4 b = *reinterpret_cast<const float4*>(in + (size_t)t * 8 + 4);
        *reinterpret_cast<short8*>(out + (size_t)t * 8) = pack2(a, b);
    }
}

// ---------------- CSR build: hist -> scan -> scatter ----------------
__global__ void hist_kernel(const int* __restrict__ ei, int* __restrict__ counts) {
    int e = blockIdx.x * 256 + threadIdx.x;
    if (e < NE) atomicAdd(&counts[ei[NE + e]], 1);
}

__global__ __launch_bounds__(1024)
void scan1_kernel(const int* __restrict__ counts, int* __restrict__ partial,
                  int* __restrict__ bsum) {
    __shared__ int wsum[16];
    int tid = threadIdx.x;
    int gid = blockIdx.x * 1024 + tid;
    int lane = tid & 63, w = tid >> 6;
    int v = (gid < NN) ? counts[gid] : 0;
    int s = v;
    #pragma unroll
    for (int o = 1; o < 64; o <<= 1) { int t = __shfl_up(s, o); if (lane >= o) s += t; }
    if (lane == 63) wsum[w] = s;
    __syncthreads();
    if (w == 0 && lane < 16) {
        int t = wsum[lane];
        #pragma unroll
        for (int o = 1; o < 16; o <<= 1) { int u = __shfl_up(t, o); if (lane >= o) t += u; }
        wsum[lane] = t;
    }
    __syncthreads();
    int base = (w > 0) ? wsum[w - 1] : 0;
    if (gid < NN) partial[gid] = base + s - v;
    if (tid == 1023) bsum[blockIdx.x] = base + s;
}

__global__ void scan2_kernel(int* __restrict__ bsum, int n) {
    int lane = threadIdx.x;
    int v = (lane < n) ? bsum[lane] : 0;
    int s = v;
    #pragma unroll
    for (int o = 1; o < 64; o <<= 1) { int t = __shfl_up(s, o); if (lane >= o) s += t; }
    if (lane < n) bsum[lane] = s - v;
}

__global__ void scatter_kernel(const int* __restrict__ ei, const int* __restrict__ partial,
                               const int* __restrict__ bsum, int* __restrict__ cursor,
                               const float* __restrict__ cd, const float* __restrict__ ea,
                               unsigned int* __restrict__ epack,
                               uint2* __restrict__ relb,
                               unsigned short* __restrict__ eab) {
    int e = blockIdx.x * 256 + threadIdx.x;
    if (e < NE) {
        int d = ei[NE + e];
        int s = ei[e];
        int pos = partial[d] + bsum[d >> 10] + atomicAdd(&cursor[d], 1);
        epack[pos] = (unsigned int)s | ((unsigned int)d << 16);
        float r0 = cd[d * 3 + 0] - cd[s * 3 + 0];
        float r1 = cd[d * 3 + 1] - cd[s * 3 + 1];
        float r2 = cd[d * 3 + 2] - cd[s * 3 + 2];
        uint2 rr;
        asm("v_cvt_pk_bf16_f32 %0, %1, %2" : "=v"(rr.x) : "v"(r0), "v"(r1));
        asm("v_cvt_pk_bf16_f32 %0, %1, %2" : "=v"(rr.y) : "v"(r2), "v"(0.0f));
        relb[pos] = rr;
        const float* eap = ea + (size_t)e * 32;
        unsigned short* eo = eab + (size_t)pos * 32;
        #pragma unroll
        for (int q = 0; q < 4; ++q) {
            float4 a = *reinterpret_cast<const float4*>(eap + q * 8);
            float4 b = *reinterpret_cast<const float4*>(eap + q * 8 + 4);
            *reinterpret_cast<short8*>(eo + q * 8) = pack2(a, b);
        }
    }
}

// ---------------- message MLP: 32x32x16 MFMA, 32 edges/wave ----------------
// 128 dst-sorted edges per block (4 waves x 32). M=32 per weight pass halves
// the per-edge weight stream from L2 (msg was ~68% of the L2 BW ceiling on
// weight re-reads at M=16). A-fragments: row=lane&31, k-chunk=(lane>>5)*8.
// C/D: col=lane&31, row=(reg&3)+8*(reg>>2)+4*(lane>>5) [m74/m101-verified].
__global__ __launch_bounds__(256, 4)
void msg_kernel(const unsigned short* __restrict__ xb, const unsigned short* __restrict__ eab,
                const unsigned int* __restrict__ epack, const uint2* __restrict__ relb,
                const unsigned short* __restrict__ W1q, const float* __restrict__ mb1,
                const unsigned short* __restrict__ W2q, const float* __restrict__ mb2,
                float* __restrict__ aggr) {
    __shared__ unsigned short sH[128 * 136];   // hidden tile, then bf16 out tile
    __shared__ int sDst[128];

    const int tid = threadIdx.x;
    const int lane = tid & 63;
    const int wid = tid >> 6;
    const int lr31 = lane & 31;        // A-row / C-col within wave's 32-slice
    const int half = lane >> 5;        // k-subchunk selector
    const int wrow = wid * 32 + lr31;  // edge row in block tile
    const int eidx = blockIdx.x * 128 + wrow;

    const unsigned int p = epack[eidx];
    const int src = (int)(p & 0xFFFFu);
    const int dst = (int)(p >> 16);
    if (half == 0) sDst[wrow] = dst;

    const unsigned short* xs = xb + (size_t)src * 128 + half * 8;
    const unsigned short* xd = xb + (size_t)dst * 128 + half * 8;
    const unsigned short* epr = eab + (size_t)eidx * 32 + half * 8;
    const uint2 rr = relb[eidx];

    const short8* w1 = reinterpret_cast<const short8*>(W1q);
    const short8* w2 = reinterpret_cast<const short8*>(W2q);

    // Layer 1: (128x320) @ (320x128); per wave 32x128 output = 4 x (32x32).
    floatx16 acc[4];
    #pragma unroll
    for (int n = 0; n < 4; ++n)
        #pragma unroll
        for (int q = 0; q < 16; ++q) acc[n][q] = 0.0f;
    NOPGUARD_INIT4x16(acc);

    // k 0..127: x_src
    #pragma unroll
    for (int s = 0; s < 8; ++s) {
        short8 a = *reinterpret_cast<const short8*>(xs + s * 16);
        const short8* wb = w1 + (s * 4) * 64 + lane;
        #pragma unroll
        for (int n = 0; n < 4; ++n) acc[n] = mfma32x32x16(a, wb[n * 64], acc[n]);
    }
    // k 128..255: x_dst
    #pragma unroll
    for (int s = 8; s < 16; ++s) {
        short8 a = *reinterpret_cast<const short8*>(xd + (s - 8) * 16);
        const short8* wb = w1 + (s * 4) * 64 + lane;
        #pragma unroll
        for (int n = 0; n < 4; ++n) acc[n] = mfma32x32x16(a, wb[n * 64], acc[n]);
    }
    // k 256..287: edge_attr
    #pragma unroll
    for (int s = 16; s < 18; ++s) {
        short8 a = *reinterpret_cast<const short8*>(epr + (s - 16) * 16);
        const short8* wb = w1 + (s * 4) * 64 + lane;
        #pragma unroll
        for (int n = 0; n < 4; ++n) acc[n] = mfma32x32x16(a, wb[n * 64], acc[n]);
    }
    // k 288..303: rel (half==0 lanes carry rel0..2; rest zero; k>=291 weights
    // are zero-padded). k 304..319 weights are all zero -> step skipped.
    {
        union { unsigned int u[4]; short8 s; } a9;
        a9.u[0] = (half == 0) ? rr.x : 0u;
        a9.u[1] = (half == 0) ? rr.y : 0u;
        a9.u[2] = 0u; a9.u[3] = 0u;
        const short8* wb = w1 + (18 * 4) * 64 + lane;
        #pragma unroll
        for (int n = 0; n < 4; ++n) acc[n] = mfma32x32x16(a9.s, wb[n * 64], acc[n]);
    }
    NOPGUARD4x16(acc);

    // Per-wave segment-head mask over this wave's 32 rows.
    WAVE_LDS_FENCE();
    unsigned int hm32;
    {
        bool head = false;
        if (lane < 32) {
            int r = wid * 32 + lane;
            head = (lane == 0) || (sDst[r] != sDst[r - 1]);
        }
        unsigned long long m = __ballot(head);
        hm32 = (unsigned int)(m & 0xFFFFFFFFull);
    }

    // bias + ReLU -> sH (bf16), wave-private 32-row slice.
    #pragma unroll
    for (int n = 0; n < 4; ++n) {
        float bias = mb1[n * 32 + lr31];
        #pragma unroll
        for (int q = 0; q < 16; ++q) {
            int crow = (q & 3) + 8 * (q >> 2) + 4 * half;
            sH[(wid * 32 + crow) * 136 + n * 32 + lr31] = f2bf(fmaxf(acc[n][q] + bias, 0.0f));
        }
    }
    WAVE_LDS_FENCE();

    // Layer 2: (128x128) @ (128x128), K=128 in 8 steps; A from sH.
    floatx16 acc2[4];
    #pragma unroll
    for (int n = 0; n < 4; ++n)
        #pragma unroll
        for (int q = 0; q < 16; ++q) acc2[n][q] = 0.0f;
    NOPGUARD_INIT4x16(acc2);

    #pragma unroll
    for (int s = 0; s < 8; ++s) {
        short8 a = *reinterpret_cast<const short8*>(&sH[wrow * 136 + s * 16 + half * 8]);
        const short8* wb = w2 + (s * 4) * 64 + lane;
        #pragma unroll
        for (int n = 0; n < 4; ++n) acc2[n] = mfma32x32x16(a, wb[n * 64], acc2[n]);
    }
    NOPGUARD4x16(acc2);
    WAVE_LDS_FENCE();   // sH reads drained before the out tile overwrites

    // bias -> bf16 LDS out tile (same wave-private rows).
    #pragma unroll
    for (int n = 0; n < 4; ++n) {
        float bias = mb2[n * 32 + lr31];
        #pragma unroll
        for (int q = 0; q < 16; ++q) {
            int crow = (q & 3) + 8 * (q >> 2) + 4 * half;
            sH[(wid * 32 + crow) * 136 + n * 32 + lr31] = f2bf(acc2[n][q] + bias);
        }
    }
    WAVE_LDS_FENCE();

    // Per-wave bitmask segmented reduce over 32 rows; lane covers cols
    // {lane, lane+64}; one atomic row per segment.
    {
        unsigned int m = hm32;
        while (m) {
            int start = __ffs(m) - 1;
            unsigned int m2 = m & (m - 1);
            int end = m2 ? (__ffs(m2) - 1) : 32;
            float sum0 = 0.0f, sum1 = 0.0f;
            for (int r = start; r < end; ++r) {
                int rw = wid * 32 + r;
                unsigned int u0 = sH[rw * 136 + lane];
                unsigned int u1 = sH[rw * 136 + 64 + lane];
                sum0 += __uint_as_float(u0 << 16);
                sum1 += __uint_as_float(u1 << 16);
            }
            int d = sDst[wid * 32 + start];
            atomicAdd(&aggr[d * 128 + lane], sum0);
            atomicAdd(&aggr[d * 128 + 64 + lane], sum1);
            m = m2;
        }
    }
}

// ---------------- node update MLP + residual + LayerNorm (unchanged, 16x16 path) ----------------
__global__
void node_kernel(const unsigned short* __restrict__ xb, const float* __restrict__ x,
                 const float* __restrict__ aggr,
                 const unsigned short* __restrict__ U1p, const float* __restrict__ ub1,
                 const unsigned short* __restrict__ U2p, const float* __restrict__ ub2,
                 const float* __restrict__ gamma, const float* __restrict__ beta,
                 float* __restrict__ out) {
    __shared__ unsigned short sH[64 * 136];

    const int tid = threadIdx.x;
    const int lane = tid & 63;
    const int wid = tid >> 6;
    const int g = lane >> 4;
    const int lr = lane & 15;
    const int arow = wid * 16 + lr;
    const int n0 = blockIdx.x * 64;

    int nd0 = n0 + arow;
    int ndc0 = (nd0 < NN) ? nd0 : (NN - 1);

    const unsigned short* xp = xb + (size_t)ndc0 * 128 + g * 8;
    const float* ap = aggr + (size_t)ndc0 * 128 + g * 8;

    short8 af[8];
    float4 ta[8];
    #pragma unroll
    for (int kk = 0; kk < 4; ++kk) {
        af[kk] = *reinterpret_cast<const short8*>(xp + kk * 32);
        ta[2 * kk]     = *reinterpret_cast<const float4*>(ap + kk * 32);
        ta[2 * kk + 1] = *reinterpret_cast<const float4*>(ap + kk * 32 + 4);
    }
    #pragma unroll
    for (int kk = 0; kk < 4; ++kk)
        af[4 + kk] = pack2(ta[2 * kk], ta[2 * kk + 1]);

    floatx4 acc[8];
    #pragma unroll
    for (int n = 0; n < 8; ++n)
        #pragma unroll
        for (int r = 0; r < 4; ++r) acc[n][r] = 0.0f;
    NOPGUARD_INIT8(acc);

    #pragma unroll
    for (int kk = 0; kk < 8; ++kk) {
        const short8* wb = reinterpret_cast<const short8*>(U1p) + (kk * 8) * 64 + lane;
        #pragma unroll
        for (int n = 0; n < 8; ++n)
            acc[n] = mfma16x16x32(af[kk], wb[n * 64], acc[n]);
    }
    NOPGUARD8(acc);

    #pragma unroll
    for (int n = 0; n < 8; ++n) {
        float bias = ub1[n * 16 + lr];
        #pragma unroll
        for (int r = 0; r < 4; ++r) {
            int row = wid * 16 + g * 4 + r;
            sH[row * 136 + n * 16 + lr] = f2bf(fmaxf(acc[n][r] + bias, 0.0f));
        }
    }
    WAVE_LDS_FENCE();

    short8 a2[4];
    #pragma unroll
    for (int kk = 0; kk < 4; ++kk)
        a2[kk] = *reinterpret_cast<const short8*>(&sH[arow * 136 + kk * 32 + g * 8]);

    floatx4 acc2[8];
    #pragma unroll
    for (int n = 0; n < 8; ++n)
        #pragma unroll
        for (int r = 0; r < 4; ++r) acc2[n][r] = 0.0f;
    NOPGUARD_INIT8(acc2);

    #pragma unroll
    for (int kk = 0; kk < 4; ++kk) {
        const short8* wb = reinterpret_cast<const short8*>(U2p) + (kk * 8) * 64 + lane;
        #pragma unroll
        for (int n = 0; n < 8; ++n)
            acc2[n] = mfma16x16x32(a2[kk], wb[n * 64], acc2[n]);
    }
    NOPGUARD8(acc2);

    #pragma unroll
    for (int r = 0; r < 4; ++r) {
        int row = wid * 16 + g * 4 + r;
        int nd = n0 + row;
        int ndc = (nd < NN) ? nd : (NN - 1);
        float vals[8];
        float s1 = 0.0f, s2 = 0.0f;
        #pragma unroll
        for (int n = 0; n < 8; ++n) {
            int col = n * 16 + lr;
            float v = acc2[n][r] + ub2[col] + x[ndc * 128 + col];
            vals[n] = v;
            s1 += v;
            s2 += v * v;
        }
        #pragma unroll
        for (int m = 1; m < 16; m <<= 1) {
            s1 += __shfl_xor(s1, m);
            s2 += __shfl_xor(s2, m);
        }
        float mean = s1 * (1.0f / 128.0f);
        float var = s2 * (1.0f / 128.0f) - mean * mean;
        float inv = rsqrtf(var + 1e-5f);
        if (nd < NN) {
            #pragma unroll
            for (int n = 0; n < 8; ++n) {
                int col = n * 16 + lr;
                out[nd * 128 + col] = (vals[n] - mean) * inv * gamma[col] + beta[col];
            }
        }
    }
}

extern "C" void kernel_launch(void* const* d_in, const int* in_sizes, int n_in,
                              void* d_out, int out_size, void* d_ws, size_t ws_size,
                              hipStream_t stream) {
    const float* x     = (const float*)d_in[0];
    const int*   ei    = (const int*)d_in[1];
    const float* ea    = (const float*)d_in[2];
    const float* cd    = (const float*)d_in[3];
    const float* mW1   = (const float*)d_in[4];
    const float* mb1   = (const float*)d_in[5];
    const float* mW2   = (const float*)d_in[6];
    const float* mb2   = (const float*)d_in[7];
    const float* uW1   = (const float*)d_in[8];
    const float* ub1   = (const float*)d_in[9];
    const float* uW2   = (const float*)d_in[10];
    const float* ub2   = (const float*)d_in[11];
    const float* gamma = (const float*)d_in[12];
    const float* beta  = (const float*)d_in[13];
    float* out = (float*)d_out;

    char* ws = (char*)d_ws;
    unsigned short* W1q = (unsigned short*)(ws);                     // 81,920 B
    unsigned short* W2q = (unsigned short*)(ws + 81920);             // 32,768 B
    unsigned short* U1p = (unsigned short*)(ws + 114688);            // 65,536 B
    unsigned short* U2p = (unsigned short*)(ws + 180224);            // 32,768 B
    int* counts  = (int*)(ws + 212992);                              // 200,704 B
    int* cursor  = (int*)(ws + 413696);                              // 200,704 B (adjacent: one memset)
    int* partial = (int*)(ws + 614400);                              // 200,704 B
    int* bsum    = (int*)(ws + 815104);                              // 256 B
    unsigned int* epack = (unsigned int*)(ws + 815360);              // 3,200,000 B
    uint2* relb  = (uint2*)(ws + 4015360);                           // 6,400,000 B
    unsigned short* xbuf = (unsigned short*)(ws + 10415360);         // 12,800,000 B
    unsigned short* eabuf = (unsigned short*)(ws + 23215360);        // 51,200,000 B
    // total ws use: 74,415,360 B

    float* aggr = out;   // aggr lives in d_out (exactly NN*HD floats)

    hipMemsetAsync(counts, 0, (size_t)(614400 - 212992), stream);
    hipMemsetAsync(aggr, 0, (size_t)NN * HD * sizeof(float), stream);

    pack_weights<<<416, 256, 0, stream>>>(mW1, mW2, uW1, uW2, W1q, W2q, U1p, U2p);
    cast_kernel<<<(NN * HD / 8 + 255) / 256, 256, 0, stream>>>(x, xbuf, NN * HD / 8);
    hist_kernel<<<(NE + 255) / 256, 256, 0, stream>>>(ei, counts);
    scan1_kernel<<<(NN + 1023) / 1024, 1024, 0, stream>>>(counts, partial, bsum);
    scan2_kernel<<<1, 64, 0, stream>>>(bsum, (NN + 1023) / 1024);
    scatter_kernel<<<(NE + 255) / 256, 256, 0, stream>>>(ei, partial, bsum, cursor, cd, ea, epack, relb, eabuf);
    msg_kernel<<<NE / 128, 256, 0, stream>>>(xbuf, eabuf, epack, relb, W1q, mb1, W2q, mb2, aggr);
    node_kernel<<<(NN + 63) / 64, 256, 0, stream>>>(xbuf, x, aggr, U1p, ub1, U2p, ub2, gamma, beta, out);
}